// Round 3
// baseline (290.823 us; speedup 1.0000x reference)
//
#include <hip/hip_runtime.h>
#include <hip/hip_bf16.h>

typedef __bf16 v4bf __attribute__((ext_vector_type(4)));
typedef __bf16 v8bf __attribute__((ext_vector_type(8)));
typedef float  v16f __attribute__((ext_vector_type(16)));
typedef float  f4v  __attribute__((ext_vector_type(4)));
typedef unsigned int u4v __attribute__((ext_vector_type(4)));

#define LOG2E 1.44269504088896340736f
#define NBIN 64

// round-to-nearest-even float -> bf16 bits
__device__ __forceinline__ unsigned short f2bf(float f) {
    union { float f; unsigned int u; } a; a.f = f;
    unsigned int r = a.u + 0x7FFFu + ((a.u >> 16) & 1u);
    return (unsigned short)(r >> 16);
}

__device__ __forceinline__ void unpack8v(u4v w, float* f) {
    #pragma unroll
    for (int i = 0; i < 4; ++i) {
        f[2 * i]     = __uint_as_float(w[i] << 16);
        f[2 * i + 1] = __uint_as_float(w[i] & 0xFFFF0000u);
    }
}

// ---------------- Phase 0: pack W^T bf16 + zero deg/hist (fused) ----------------
// k & q weights pre-scaled by log2(e); k additionally NEGATED so the
// gather kernel reads nk = -k' directly (sigmoid = rcp(1 + 2^(nk - q'))).
__global__ __launch_bounds__(256) void prep_w_zero(
    const float* __restrict__ Wk, const float* __restrict__ Wq,
    const float* __restrict__ Wv, const float* __restrict__ Ws,
    unsigned short* __restrict__ Wt, int* __restrict__ deg,
    int* __restrict__ hist, int* __restrict__ binCnt, int N)
{
    int i = blockIdx.x * 256 + threadIdx.x;      // 512 blocks -> 131072 threads
    if (i < 65536) {
        int m = i >> 14;
        int r = i & 16383;
        int n = r >> 7, k = r & 127;
        const float* W = (m == 0) ? Wk : (m == 1) ? Wq : (m == 2) ? Wv : Ws;
        float scale = (m == 0) ? -LOG2E : (m == 1) ? LOG2E : 1.0f;
        Wt[i] = f2bf(W[k * 128 + n] * scale);
    }
    if (i < N) deg[i] = 0;
    if (i < NBIN) { hist[i] = 0; binCnt[i] = 0; }
}

// ---------------- Phase 1: fused MFMA GEMM, x read once ----------------
__global__ __launch_bounds__(1024, 4) void gemm_fused(
    const float* __restrict__ x, int N,
    const unsigned short* __restrict__ Wt,
    const float* __restrict__ bk, const float* __restrict__ bq,
    const float* __restrict__ bv, const float* __restrict__ bs,
    unsigned short* __restrict__ kws, unsigned short* __restrict__ qv,
    float* __restrict__ out)
{
    __shared__ __align__(16) unsigned short xs[32 * 132];
    const int t   = threadIdx.x;
    const int wid = t >> 6;          // 0..15
    const int m   = wid >> 2;        // matrix
    const int ct  = wid & 3;         // col tile
    const int l   = t & 63;
    const int col = ct * 32 + (l & 31);
    const int kb  = (l >> 5) * 8;

    v8bf b[8];
    {
        const unsigned short* wp = Wt + m * 16384 + col * 128 + kb;
        #pragma unroll
        for (int c = 0; c < 8; ++c) b[c] = *(const v8bf*)(wp + c * 16);
    }
    const float* bvec = (m == 0) ? bk : (m == 1) ? bq : (m == 2) ? bv : bs;
    const float bcol = bvec[col] * ((m == 0) ? -LOG2E : (m == 1) ? LOG2E : 1.0f);
    unsigned short* dst; int dstride;
    if (m == 0)      { dst = kws;      dstride = 128; }
    else if (m == 1) { dst = qv;       dstride = 256; }
    else             { dst = qv + 128; dstride = 256; }   // m==2 (v half)

    const int srow = t >> 5;         // 0..31
    const int sk4  = (t & 31) << 2;  // 0..124
    const int rowb = 4 * (l >> 5);

    const int ntiles = (N + 31) >> 5;
    int tile = blockIdx.x;
    if (tile >= ntiles) return;

    float4 stg = make_float4(0.f, 0.f, 0.f, 0.f);
    {
        int gr = tile * 32 + srow;
        if (gr < N) stg = *(const float4*)(x + (size_t)gr * 128 + sk4);
    }

    const unsigned short* ap = xs + (l & 31) * 132 + kb;

    while (true) {
        ushort4 pk;
        pk.x = f2bf(stg.x); pk.y = f2bf(stg.y);
        pk.z = f2bf(stg.z); pk.w = f2bf(stg.w);
        *(ushort4*)(xs + srow * 132 + sk4) = pk;
        __syncthreads();

        int next = tile + gridDim.x;
        if (next < ntiles) {
            int gr = next * 32 + srow;
            stg = (gr < N) ? *(const float4*)(x + (size_t)gr * 128 + sk4)
                           : make_float4(0.f, 0.f, 0.f, 0.f);
        }

        v16f acc = {};
        #pragma unroll
        for (int c = 0; c < 8; ++c) {
            v4bf a0 = *(const v4bf*)(ap + c * 16);
            v4bf a1 = *(const v4bf*)(ap + c * 16 + 4);
            v8bf a = __builtin_shufflevector(a0, a1, 0, 1, 2, 3, 4, 5, 6, 7);
            acc = __builtin_amdgcn_mfma_f32_32x32x16_bf16(a, b[c], acc, 0, 0, 0);
        }

        const int r0 = tile * 32 + rowb;
        if (m == 3) {
            #pragma unroll
            for (int reg = 0; reg < 16; ++reg) {
                int row = r0 + (reg & 3) + 8 * (reg >> 2);
                if (row < N) out[(size_t)row * 128 + col] = acc[reg] + bcol;
            }
        } else {
            #pragma unroll
            for (int reg = 0; reg < 16; ++reg) {
                int row = r0 + (reg & 3) + 8 * (reg >> 2);
                if (row < N) dst[(size_t)row * dstride + col] = f2bf(acc[reg] + bcol);
            }
        }

        tile = next;
        if (tile >= ntiles) break;
        __syncthreads();
    }
}

// ---------------- Phase 2: device-built CSR (single-atomic counting sort) ----------------

__global__ __launch_bounds__(256) void count_pos(
    const int* __restrict__ ei, int E, int* __restrict__ deg,
    int* __restrict__ pos)
{
    int e = blockIdx.x * 256 + threadIdx.x;
    if (e >= E) return;
    pos[e] = atomicAdd(&deg[ei[E + e]], 1);   // dst
}

// scan of degrees into rowStart (per-1024 chunks) + fused 64-bin degree
// histogram (for the node degree-sort).
__global__ __launch_bounds__(256) void scan_chunks(
    const int* __restrict__ deg, int N, int* __restrict__ rowStart,
    int* __restrict__ chunkTot, int* __restrict__ hist)
{
    __shared__ int sums[256];
    __shared__ int h[NBIN];
    const int t = threadIdx.x;
    if (t < NBIN) h[t] = 0;
    const int base = blockIdx.x * 1024 + t * 4;
    int d0 = 0, d1 = 0, d2 = 0, d3 = 0;
    if (base + 3 < N) {
        int4 dd = *(const int4*)(deg + base);
        d0 = dd.x; d1 = dd.y; d2 = dd.z; d3 = dd.w;
    } else {
        if (base + 0 < N) d0 = deg[base + 0];
        if (base + 1 < N) d1 = deg[base + 1];
        if (base + 2 < N) d2 = deg[base + 2];
        if (base + 3 < N) d3 = deg[base + 3];
    }
    int tot = d0 + d1 + d2 + d3;
    sums[t] = tot;
    __syncthreads();
    // LDS histogram (only real nodes!)
    if (base + 0 < N) atomicAdd(&h[min(d0, NBIN - 1)], 1);
    if (base + 1 < N) atomicAdd(&h[min(d1, NBIN - 1)], 1);
    if (base + 2 < N) atomicAdd(&h[min(d2, NBIN - 1)], 1);
    if (base + 3 < N) atomicAdd(&h[min(d3, NBIN - 1)], 1);
    #pragma unroll
    for (int off = 1; off < 256; off <<= 1) {
        int v = (t >= off) ? sums[t - off] : 0;
        __syncthreads();
        sums[t] += v;
        __syncthreads();
    }
    int excl = sums[t] - tot;
    if (base + 0 < N) rowStart[base + 0] = excl;
    if (base + 1 < N) rowStart[base + 1] = excl + d0;
    if (base + 2 < N) rowStart[base + 2] = excl + d0 + d1;
    if (base + 3 < N) rowStart[base + 3] = excl + d0 + d1 + d2;
    if (t == 255) chunkTot[blockIdx.x] = sums[255];
    if (t < NBIN && h[t] > 0) atomicAdd(&hist[t], h[t]);
}

// add chunk offsets; block 0 additionally computes the DESCENDING
// exclusive scan of the degree histogram (binStart) for the node sort.
__global__ __launch_bounds__(256) void add_offsets(
    int* __restrict__ rowStart, const int* __restrict__ chunkTot,
    const int* __restrict__ hist, int* __restrict__ binStart,
    int N, int nChunks)
{
    __shared__ int s[128];
    const int t = threadIdx.x;
    if (t < 128) s[t] = (t < nChunks) ? chunkTot[t] : 0;
    __syncthreads();
    #pragma unroll
    for (int off = 1; off < 128; off <<= 1) {
        int u = 0;
        if (t < 128 && t >= off) u = s[t - off];
        __syncthreads();
        if (t < 128) s[t] += u;
        __syncthreads();
    }
    const int coff = (blockIdx.x == 0) ? 0 : s[blockIdx.x - 1];
    const int base = blockIdx.x * 1024 + t * 4;
    if (base + 3 < N) {
        int4 r = *(const int4*)(rowStart + base);
        r.x += coff; r.y += coff; r.z += coff; r.w += coff;
        *(int4*)(rowStart + base) = r;
    } else {
        #pragma unroll
        for (int j = 0; j < 4; ++j) {
            if (base + j < N) rowStart[base + j] += coff;
        }
    }
    // tiny serial descending scan: high-degree bins get the low slots
    if (blockIdx.x == 0 && t == 0) {
        int run = 0;
        for (int b = NBIN - 1; b >= 0; --b) { binStart[b] = run; run += hist[b]; }
    }
}

__global__ __launch_bounds__(256) void fill_csr(
    const int* __restrict__ ei, int E,
    const int* __restrict__ rowStart, const int* __restrict__ pos,
    int* __restrict__ elist)
{
    int e = blockIdx.x * 256 + threadIdx.x;
    if (e >= E) return;
    int s = ei[e];
    int d = ei[E + e];
    elist[rowStart[d] + pos[e]] = s;   // atomic-free scatter
}

// scatter nodes into degree-sorted perm (counting sort; order within a
// bin is irrelevant). Per-block LDS ranks -> one global atomic per bin.
__global__ __launch_bounds__(256) void scatter_perm(
    const int* __restrict__ deg, int N, const int* __restrict__ binStart,
    int* __restrict__ binCnt, int* __restrict__ perm)
{
    __shared__ int h[NBIN];
    __shared__ int sbase[NBIN];
    const int t = threadIdx.x;
    if (t < NBIN) h[t] = 0;
    __syncthreads();
    int i = blockIdx.x * 256 + t;
    int b = 0, rank = 0;
    if (i < N) {
        b = min(deg[i], NBIN - 1);
        rank = atomicAdd(&h[b], 1);
    }
    __syncthreads();
    if (t < NBIN && h[t] > 0) sbase[t] = atomicAdd(&binCnt[t], h[t]);
    __syncthreads();
    if (i < N) perm[binStart[b] + sbase[b] + rank] = i;
}

// ---------------- Phase 3: owner-computes aggregation (no atomics) ----------------
// 4 nodes/wave (16 lanes each) in DEGREE-SORTED order: the 4 nodes of a
// wave have (near-)equal degree -> no lockstep-divergence waste, and
// high-degree waves launch first (tail scheduling). Chunk-4 exact-trip
// loop with 2-deep ping-pong: next chunk's 8 gathers issued before the
// current chunk's math. Plain (cached) loads/stores throughout — R2
// showed non-temporal hints cause HBM write amplification (50->102 MB).
__global__ __launch_bounds__(256, 4) void gather_agg(
    const int* __restrict__ perm,
    const int* __restrict__ rowStart, const int* __restrict__ deg,
    const int* __restrict__ elist,
    const unsigned short* __restrict__ kws,
    const unsigned short* __restrict__ qv,
    float* __restrict__ out, int N)
{
    int gid = blockIdx.x * 256 + threadIdx.x;
    int ni = gid >> 4;
    if (ni >= N) return;
    const int node = perm[ni];
    int fo = (gid & 15) << 3;   // 8 feats per lane

    // issue long-latency independent loads first
    float* orow = out + (size_t)node * 128 + fo;
    f4v o0 = *(const f4v*)(orow);
    f4v o1 = *(const f4v*)(orow + 4);
    u4v kraw = *(const u4v*)(kws + (size_t)node * 128 + fo);  // holds -k'
    const int p0 = rowStart[node];
    const int dg = deg[node];

    float nkf[8];
    unpack8v(kraw, nkf);
    float acc[8] = {};

    const unsigned short* qvb = qv + fo;
    const int e = p0 + dg;

    if (dg > 0) {
        u4v qA[4], vA[4], qB[4], vB[4];

#define LOADC(b, qr, vr)                                                     \
        {                                                                    \
            _Pragma("unroll")                                                \
            for (int s = 0; s < 4; ++s) {                                    \
                int pp = (b) + s;                                            \
                int ix = elist[pp < e ? pp : e - 1];                         \
                const unsigned short* r = qvb + (ix << 8);                   \
                qr[s] = *(const u4v*)(r);                                    \
                vr[s] = *(const u4v*)(r + 128);                              \
            }                                                                \
        }

#define COMP(b, qr, vr)                                                     \
        {                                                                   \
            _Pragma("unroll")                                               \
            for (int s = 0; s < 4; ++s) {                                   \
                u4v vv = vr[s];                                             \
                if ((b) + s >= e) { vv[0]=0u; vv[1]=0u; vv[2]=0u; vv[3]=0u; } \
                float qf[8], vf[8];                                         \
                unpack8v(qr[s], qf);                                        \
                unpack8v(vv, vf);                                           \
                _Pragma("unroll")                                           \
                for (int j = 0; j < 8; ++j) {                               \
                    float ex = __builtin_amdgcn_exp2f(nkf[j] - qf[j]);      \
                    acc[j] = fmaf(__builtin_amdgcn_rcpf(1.0f + ex), vf[j], acc[j]); \
                }                                                           \
            }                                                               \
        }

        int base = p0;
        LOADC(base, qA, vA);
        while (true) {
            int nb = base + 4;
            if (nb < e) {
                LOADC(nb, qB, vB);          // pipeline: issue next chunk's loads
                COMP(base, qA, vA);         // ...then compute current chunk
                base = nb;
                nb = base + 4;
                if (nb < e) {
                    LOADC(nb, qA, vA);
                    COMP(base, qB, vB);
                    base = nb;
                } else {
                    COMP(base, qB, vB);
                    break;
                }
            } else {
                COMP(base, qA, vA);
                break;
            }
        }
#undef LOADC
#undef COMP
    }

    o0[0] += acc[0]; o0[1] += acc[1]; o0[2] += acc[2]; o0[3] += acc[3];
    o1[0] += acc[4]; o1[1] += acc[5]; o1[2] += acc[6]; o1[3] += acc[7];
    *(f4v*)(orow)     = o0;
    *(f4v*)(orow + 4) = o1;
}

extern "C" void kernel_launch(void* const* d_in, const int* in_sizes, int n_in,
                              void* d_out, int out_size, void* d_ws, size_t ws_size,
                              hipStream_t stream) {
    const float* x    = (const float*)d_in[0];
    const int*   ei   = (const int*)d_in[1];
    const float* Wk   = (const float*)d_in[3];
    const float* bk   = (const float*)d_in[4];
    const float* Wq   = (const float*)d_in[5];
    const float* bq   = (const float*)d_in[6];
    const float* Wv   = (const float*)d_in[7];
    const float* bv   = (const float*)d_in[8];
    const float* Ws   = (const float*)d_in[9];
    const float* bias = (const float*)d_in[10];

    const int N = in_sizes[0] / 128;
    const int E = in_sizes[1] / 2;
    float* out = (float*)d_out;

    // workspace layout
    unsigned short* kws = (unsigned short*)d_ws;        // N*128 bf16 (-k', scaled)
    unsigned short* qv  = kws + (size_t)N * 128;        // N*256 bf16 (q'|v)
    int* deg      = (int*)(qv + (size_t)N * 256);
    int* rowStart = deg + N;
    int* chunkTot = rowStart + N;
    int* pos      = chunkTot + 128;                     // E ints (per-edge slot)
    int* elist    = pos + E;
    int* perm     = elist + E;                          // N ints (degree-sorted)
    int* hist     = perm + N;                           // 64
    int* binStart = hist + NBIN;                        // 64
    int* binCnt   = binStart + NBIN;                    // 64
    unsigned short* Wt = (unsigned short*)(binCnt + NBIN);

    const int nChunks = (N + 1023) / 1024;

    prep_w_zero<<<512, 256, 0, stream>>>(Wk, Wq, Wv, Ws, Wt, deg, hist, binCnt, N);
    gemm_fused<<<1024, 1024, 0, stream>>>(
        x, N, Wt, bk, bq, bv, bias, kws, qv, out);

    count_pos<<<(E + 255) / 256, 256, 0, stream>>>(ei, E, deg, pos);
    scan_chunks<<<nChunks, 256, 0, stream>>>(deg, N, rowStart, chunkTot, hist);
    add_offsets<<<nChunks, 256, 0, stream>>>(rowStart, chunkTot, hist, binStart, N, nChunks);
    fill_csr<<<(E + 255) / 256, 256, 0, stream>>>(ei, E, rowStart, pos, elist);
    scatter_perm<<<(N + 255) / 256, 256, 0, stream>>>(deg, N, binStart, binCnt, perm);

    gather_agg<<<((size_t)N * 16 + 255) / 256, 256, 0, stream>>>(
        perm, rowStart, deg, elist, kws, qv, out, N);
}

// Round 4
// 281.015 us; speedup vs baseline: 1.0349x; 1.0349x over previous
//
#include <hip/hip_runtime.h>
#include <hip/hip_bf16.h>

typedef __bf16 v4bf __attribute__((ext_vector_type(4)));
typedef __bf16 v8bf __attribute__((ext_vector_type(8)));
typedef float  v16f __attribute__((ext_vector_type(16)));
typedef float  f4v  __attribute__((ext_vector_type(4)));
typedef unsigned int u4v __attribute__((ext_vector_type(4)));

#define LOG2E 1.44269504088896340736f
#define NBIN 64

// round-to-nearest-even float -> bf16 bits
__device__ __forceinline__ unsigned short f2bf(float f) {
    union { float f; unsigned int u; } a; a.f = f;
    unsigned int r = a.u + 0x7FFFu + ((a.u >> 16) & 1u);
    return (unsigned short)(r >> 16);
}

__device__ __forceinline__ void unpack8v(u4v w, float* f) {
    #pragma unroll
    for (int i = 0; i < 4; ++i) {
        f[2 * i]     = __uint_as_float(w[i] << 16);
        f[2 * i + 1] = __uint_as_float(w[i] & 0xFFFF0000u);
    }
}

// ---------------- Phase 0: pack W^T bf16 + zero deg (fused) ----------------
// k & q weights pre-scaled by log2(e); k additionally NEGATED so the
// gather kernel reads nk = -k' directly (sigmoid = rcp(1 + 2^(nk - q'))).
__global__ __launch_bounds__(256) void prep_w_zero(
    const float* __restrict__ Wk, const float* __restrict__ Wq,
    const float* __restrict__ Wv, const float* __restrict__ Ws,
    unsigned short* __restrict__ Wt, int* __restrict__ deg, int N)
{
    int i = blockIdx.x * 256 + threadIdx.x;      // 512 blocks -> 131072 threads
    if (i < 65536) {
        int m = i >> 14;
        int r = i & 16383;
        int n = r >> 7, k = r & 127;
        const float* W = (m == 0) ? Wk : (m == 1) ? Wq : (m == 2) ? Wv : Ws;
        float scale = (m == 0) ? -LOG2E : (m == 1) ? LOG2E : 1.0f;
        Wt[i] = f2bf(W[k * 128 + n] * scale);
    }
    if (i < N) deg[i] = 0;
}

// ---------------- Phase 1: fused MFMA GEMM, x read once ----------------
__global__ __launch_bounds__(1024, 4) void gemm_fused(
    const float* __restrict__ x, int N,
    const unsigned short* __restrict__ Wt,
    const float* __restrict__ bk, const float* __restrict__ bq,
    const float* __restrict__ bv, const float* __restrict__ bs,
    unsigned short* __restrict__ kws, unsigned short* __restrict__ qv,
    float* __restrict__ out)
{
    __shared__ __align__(16) unsigned short xs[32 * 132];
    const int t   = threadIdx.x;
    const int wid = t >> 6;          // 0..15
    const int m   = wid >> 2;        // matrix
    const int ct  = wid & 3;         // col tile
    const int l   = t & 63;
    const int col = ct * 32 + (l & 31);
    const int kb  = (l >> 5) * 8;

    v8bf b[8];
    {
        const unsigned short* wp = Wt + m * 16384 + col * 128 + kb;
        #pragma unroll
        for (int c = 0; c < 8; ++c) b[c] = *(const v8bf*)(wp + c * 16);
    }
    const float* bvec = (m == 0) ? bk : (m == 1) ? bq : (m == 2) ? bv : bs;
    const float bcol = bvec[col] * ((m == 0) ? -LOG2E : (m == 1) ? LOG2E : 1.0f);
    unsigned short* dst; int dstride;
    if (m == 0)      { dst = kws;      dstride = 128; }
    else if (m == 1) { dst = qv;       dstride = 256; }
    else             { dst = qv + 128; dstride = 256; }   // m==2 (v half)

    const int srow = t >> 5;         // 0..31
    const int sk4  = (t & 31) << 2;  // 0..124
    const int rowb = 4 * (l >> 5);

    const int ntiles = (N + 31) >> 5;
    int tile = blockIdx.x;
    if (tile >= ntiles) return;

    float4 stg = make_float4(0.f, 0.f, 0.f, 0.f);
    {
        int gr = tile * 32 + srow;
        if (gr < N) stg = *(const float4*)(x + (size_t)gr * 128 + sk4);
    }

    const unsigned short* ap = xs + (l & 31) * 132 + kb;

    while (true) {
        ushort4 pk;
        pk.x = f2bf(stg.x); pk.y = f2bf(stg.y);
        pk.z = f2bf(stg.z); pk.w = f2bf(stg.w);
        *(ushort4*)(xs + srow * 132 + sk4) = pk;
        __syncthreads();

        int next = tile + gridDim.x;
        if (next < ntiles) {
            int gr = next * 32 + srow;
            stg = (gr < N) ? *(const float4*)(x + (size_t)gr * 128 + sk4)
                           : make_float4(0.f, 0.f, 0.f, 0.f);
        }

        v16f acc = {};
        #pragma unroll
        for (int c = 0; c < 8; ++c) {
            v4bf a0 = *(const v4bf*)(ap + c * 16);
            v4bf a1 = *(const v4bf*)(ap + c * 16 + 4);
            v8bf a = __builtin_shufflevector(a0, a1, 0, 1, 2, 3, 4, 5, 6, 7);
            acc = __builtin_amdgcn_mfma_f32_32x32x16_bf16(a, b[c], acc, 0, 0, 0);
        }

        const int r0 = tile * 32 + rowb;
        if (m == 3) {
            #pragma unroll
            for (int reg = 0; reg < 16; ++reg) {
                int row = r0 + (reg & 3) + 8 * (reg >> 2);
                if (row < N) out[(size_t)row * 128 + col] = acc[reg] + bcol;
            }
        } else {
            #pragma unroll
            for (int reg = 0; reg < 16; ++reg) {
                int row = r0 + (reg & 3) + 8 * (reg >> 2);
                if (row < N) dst[(size_t)row * dstride + col] = f2bf(acc[reg] + bcol);
            }
        }

        tile = next;
        if (tile >= ntiles) break;
        __syncthreads();
    }
}

// ---------------- Phase 2: device-built CSR (single-atomic counting sort) ----------------

__global__ __launch_bounds__(256) void count_pos(
    const int* __restrict__ ei, int E, int* __restrict__ deg,
    int* __restrict__ pos)
{
    int e = blockIdx.x * 256 + threadIdx.x;
    if (e >= E) return;
    pos[e] = atomicAdd(&deg[ei[E + e]], 1);   // dst
}

__global__ __launch_bounds__(256) void scan_chunks(
    const int* __restrict__ deg, int N, int* __restrict__ rowStart,
    int* __restrict__ chunkTot)
{
    __shared__ int sums[256];
    const int t = threadIdx.x;
    const int base = blockIdx.x * 1024 + t * 4;
    int d0 = 0, d1 = 0, d2 = 0, d3 = 0;
    if (base + 3 < N) {
        int4 dd = *(const int4*)(deg + base);
        d0 = dd.x; d1 = dd.y; d2 = dd.z; d3 = dd.w;
    } else {
        if (base + 0 < N) d0 = deg[base + 0];
        if (base + 1 < N) d1 = deg[base + 1];
        if (base + 2 < N) d2 = deg[base + 2];
        if (base + 3 < N) d3 = deg[base + 3];
    }
    int tot = d0 + d1 + d2 + d3;
    sums[t] = tot;
    __syncthreads();
    #pragma unroll
    for (int off = 1; off < 256; off <<= 1) {
        int v = (t >= off) ? sums[t - off] : 0;
        __syncthreads();
        sums[t] += v;
        __syncthreads();
    }
    int excl = sums[t] - tot;
    if (base + 0 < N) rowStart[base + 0] = excl;
    if (base + 1 < N) rowStart[base + 1] = excl + d0;
    if (base + 2 < N) rowStart[base + 2] = excl + d0 + d1;
    if (base + 3 < N) rowStart[base + 3] = excl + d0 + d1 + d2;
    if (t == 255) chunkTot[blockIdx.x] = sums[255];
}

// add chunk offsets; each block re-scans the (<=128) chunk totals in LDS
__global__ __launch_bounds__(256) void add_offsets(
    int* __restrict__ rowStart, const int* __restrict__ chunkTot,
    int N, int nChunks)
{
    __shared__ int s[128];
    const int t = threadIdx.x;
    if (t < 128) s[t] = (t < nChunks) ? chunkTot[t] : 0;
    __syncthreads();
    #pragma unroll
    for (int off = 1; off < 128; off <<= 1) {
        int u = 0;
        if (t < 128 && t >= off) u = s[t - off];
        __syncthreads();
        if (t < 128) s[t] += u;
        __syncthreads();
    }
    const int coff = (blockIdx.x == 0) ? 0 : s[blockIdx.x - 1];
    const int base = blockIdx.x * 1024 + t * 4;
    if (base + 3 < N) {
        int4 r = *(const int4*)(rowStart + base);
        r.x += coff; r.y += coff; r.z += coff; r.w += coff;
        *(int4*)(rowStart + base) = r;
    } else {
        #pragma unroll
        for (int j = 0; j < 4; ++j) {
            if (base + j < N) rowStart[base + j] += coff;
        }
    }
}

// fill CSR (atomic-free scatter) + fused LOCAL degree-sort permutation:
// each 256-node window is counting-sorted by degree entirely in-block
// (LDS hist + wave-shfl scan). Keeps wave-level degree equality for the
// gather while confining perm to a 128KB out/kws window (L2-friendly) —
// R3's GLOBAL sort scattered out rows device-wide and doubled WRITE_SIZE.
__global__ __launch_bounds__(256) void fill_csr_perm(
    const int* __restrict__ ei, int E,
    const int* __restrict__ rowStart, const int* __restrict__ pos,
    int* __restrict__ elist,
    const int* __restrict__ deg, int N, int* __restrict__ perm)
{
    __shared__ int h[NBIN];
    __shared__ int boff[NBIN];
    const int t = threadIdx.x;
    const int nbase = blockIdx.x * 256;

    if (nbase < N) {                 // block-uniform branch (barriers safe)
        if (t < NBIN) h[t] = 0;
        __syncthreads();
        int i = nbase + t;
        int bin = 0, rank = 0;
        if (i < N) {
            bin = min(deg[i], NBIN - 1);
            rank = atomicAdd(&h[bin], 1);
        }
        __syncthreads();
        if (t < NBIN) {              // one wave: shfl inclusive scan -> exclusive
            int v = h[t];
            int inc = v;
            #pragma unroll
            for (int off = 1; off < NBIN; off <<= 1) {
                int u = __shfl_up(inc, off);
                if ((t & 63) >= off) inc += u;
            }
            boff[t] = inc - v;
        }
        __syncthreads();
        if (i < N) perm[nbase + boff[bin] + rank] = i;
    }

    int e = nbase + t;
    if (e < E) {
        int s = ei[e];
        int d = ei[E + e];
        elist[rowStart[d] + pos[e]] = s;   // atomic-free scatter
    }
}

// ---------------- Phase 3: owner-computes aggregation (no atomics) ----------------
// 4 nodes/wave (16 lanes each) in LOCALLY degree-sorted order: equal trip
// counts within a wave, but out/kws stay within a 128KB window. Chunk-4
// exact-trip loop with 2-deep ping-pong. out RMW moved AFTER the loop so
// read->add->store are adjacent (line hot in L2 at store time -> full-line
// dirty eviction; R3's start-of-kernel read caused store-miss write
// amplification, WRITE_SIZE 50->100MB).
__global__ __launch_bounds__(256, 4) void gather_agg(
    const int* __restrict__ perm,
    const int* __restrict__ rowStart, const int* __restrict__ deg,
    const int* __restrict__ elist,
    const unsigned short* __restrict__ kws,
    const unsigned short* __restrict__ qv,
    float* __restrict__ out, int N)
{
    int gid = blockIdx.x * 256 + threadIdx.x;
    int ni = gid >> 4;
    if (ni >= N) return;
    const int node = perm[ni];
    int fo = (gid & 15) << 3;   // 8 feats per lane

    u4v kraw = *(const u4v*)(kws + (size_t)node * 128 + fo);  // holds -k'
    const int p0 = rowStart[node];
    const int dg = deg[node];

    float nkf[8];
    unpack8v(kraw, nkf);
    float acc[8] = {};

    const unsigned short* qvb = qv + fo;
    const int e = p0 + dg;

    if (dg > 0) {
        u4v qA[4], vA[4], qB[4], vB[4];

#define LOADC(b, qr, vr)                                                     \
        {                                                                    \
            _Pragma("unroll")                                                \
            for (int s = 0; s < 4; ++s) {                                    \
                int pp = (b) + s;                                            \
                int ix = elist[pp < e ? pp : e - 1];                         \
                const unsigned short* r = qvb + (ix << 8);                   \
                qr[s] = *(const u4v*)(r);                                    \
                vr[s] = *(const u4v*)(r + 128);                              \
            }                                                                \
        }

#define COMP(b, qr, vr)                                                     \
        {                                                                   \
            _Pragma("unroll")                                               \
            for (int s = 0; s < 4; ++s) {                                   \
                u4v vv = vr[s];                                             \
                if ((b) + s >= e) { vv[0]=0u; vv[1]=0u; vv[2]=0u; vv[3]=0u; } \
                float qf[8], vf[8];                                         \
                unpack8v(qr[s], qf);                                        \
                unpack8v(vv, vf);                                           \
                _Pragma("unroll")                                           \
                for (int j = 0; j < 8; ++j) {                               \
                    float ex = __builtin_amdgcn_exp2f(nkf[j] - qf[j]);      \
                    acc[j] = fmaf(__builtin_amdgcn_rcpf(1.0f + ex), vf[j], acc[j]); \
                }                                                           \
            }                                                               \
        }

        int base = p0;
        LOADC(base, qA, vA);
        while (true) {
            int nb = base + 4;
            if (nb < e) {
                LOADC(nb, qB, vB);          // pipeline: issue next chunk's loads
                COMP(base, qA, vA);         // ...then compute current chunk
                base = nb;
                nb = base + 4;
                if (nb < e) {
                    LOADC(nb, qA, vA);
                    COMP(base, qB, vB);
                    base = nb;
                } else {
                    COMP(base, qB, vB);
                    break;
                }
            } else {
                COMP(base, qA, vA);
                break;
            }
        }
#undef LOADC
#undef COMP
    }

    // RMW kept tight: read -> add -> store (line stays hot in L2)
    float* orow = out + (size_t)node * 128 + fo;
    f4v o0 = *(const f4v*)(orow);
    f4v o1 = *(const f4v*)(orow + 4);
    o0[0] += acc[0]; o0[1] += acc[1]; o0[2] += acc[2]; o0[3] += acc[3];
    o1[0] += acc[4]; o1[1] += acc[5]; o1[2] += acc[6]; o1[3] += acc[7];
    *(f4v*)(orow)     = o0;
    *(f4v*)(orow + 4) = o1;
}

extern "C" void kernel_launch(void* const* d_in, const int* in_sizes, int n_in,
                              void* d_out, int out_size, void* d_ws, size_t ws_size,
                              hipStream_t stream) {
    const float* x    = (const float*)d_in[0];
    const int*   ei   = (const int*)d_in[1];
    const float* Wk   = (const float*)d_in[3];
    const float* bk   = (const float*)d_in[4];
    const float* Wq   = (const float*)d_in[5];
    const float* bq   = (const float*)d_in[6];
    const float* Wv   = (const float*)d_in[7];
    const float* bv   = (const float*)d_in[8];
    const float* Ws   = (const float*)d_in[9];
    const float* bias = (const float*)d_in[10];

    const int N = in_sizes[0] / 128;
    const int E = in_sizes[1] / 2;
    float* out = (float*)d_out;

    // workspace layout
    unsigned short* kws = (unsigned short*)d_ws;        // N*128 bf16 (-k', scaled)
    unsigned short* qv  = kws + (size_t)N * 128;        // N*256 bf16 (q'|v)
    int* deg      = (int*)(qv + (size_t)N * 256);
    int* rowStart = deg + N;
    int* chunkTot = rowStart + N;
    int* pos      = chunkTot + 128;                     // E ints (per-edge slot)
    int* elist    = pos + E;
    int* perm     = elist + E;                          // N ints (local sort)
    unsigned short* Wt = (unsigned short*)(perm + N);

    const int nChunks = (N + 1023) / 1024;

    prep_w_zero<<<512, 256, 0, stream>>>(Wk, Wq, Wv, Ws, Wt, deg, N);
    gemm_fused<<<1024, 1024, 0, stream>>>(
        x, N, Wt, bk, bq, bv, bias, kws, qv, out);

    count_pos<<<(E + 255) / 256, 256, 0, stream>>>(ei, E, deg, pos);
    scan_chunks<<<nChunks, 256, 0, stream>>>(deg, N, rowStart, chunkTot);
    add_offsets<<<nChunks, 256, 0, stream>>>(rowStart, chunkTot, N, nChunks);
    fill_csr_perm<<<(E + 255) / 256, 256, 0, stream>>>(
        ei, E, rowStart, pos, elist, deg, N, perm);

    gather_agg<<<((size_t)N * 16 + 255) / 256, 256, 0, stream>>>(
        perm, rowStart, deg, elist, kws, qv, out, N);
}

// Round 6
// 278.292 us; speedup vs baseline: 1.0450x; 1.0098x over previous
//
#include <hip/hip_runtime.h>
#include <hip/hip_bf16.h>

typedef __bf16 v4bf __attribute__((ext_vector_type(4)));
typedef __bf16 v8bf __attribute__((ext_vector_type(8)));
typedef float  v16f __attribute__((ext_vector_type(16)));
typedef float  f4v  __attribute__((ext_vector_type(4)));
typedef unsigned int u4v __attribute__((ext_vector_type(4)));

#define LOG2E 1.44269504088896340736f
#define NBIN 64

// round-to-nearest-even float -> bf16 bits
__device__ __forceinline__ unsigned short f2bf(float f) {
    union { float f; unsigned int u; } a; a.f = f;
    unsigned int r = a.u + 0x7FFFu + ((a.u >> 16) & 1u);
    return (unsigned short)(r >> 16);
}

__device__ __forceinline__ void unpack8v(u4v w, float* f) {
    #pragma unroll
    for (int i = 0; i < 4; ++i) {
        f[2 * i]     = __uint_as_float(w[i] << 16);
        f[2 * i + 1] = __uint_as_float(w[i] & 0xFFFF0000u);
    }
}

// ---------------- Phase 0: pack W^T bf16 + zero deg (fused) ----------------
// k & q weights pre-scaled by log2(e); k additionally NEGATED so the
// gather kernel reads nk = -k' directly (sigmoid = rcp(1 + 2^(nk - q'))).
__global__ __launch_bounds__(256) void prep_w_zero(
    const float* __restrict__ Wk, const float* __restrict__ Wq,
    const float* __restrict__ Wv, const float* __restrict__ Ws,
    unsigned short* __restrict__ Wt, int* __restrict__ deg, int N)
{
    int i = blockIdx.x * 256 + threadIdx.x;      // 512 blocks -> 131072 threads
    if (i < 65536) {
        int m = i >> 14;
        int r = i & 16383;
        int n = r >> 7, k = r & 127;
        const float* W = (m == 0) ? Wk : (m == 1) ? Wq : (m == 2) ? Wv : Ws;
        float scale = (m == 0) ? -LOG2E : (m == 1) ? LOG2E : 1.0f;
        Wt[i] = f2bf(W[k * 128 + n] * scale);
    }
    if (i < N) deg[i] = 0;
}

// ---------------- Phase 1: fused MFMA GEMM, x read once ----------------
__global__ __launch_bounds__(1024, 4) void gemm_fused(
    const float* __restrict__ x, int N,
    const unsigned short* __restrict__ Wt,
    const float* __restrict__ bk, const float* __restrict__ bq,
    const float* __restrict__ bv, const float* __restrict__ bs,
    unsigned short* __restrict__ kws, unsigned short* __restrict__ qv,
    float* __restrict__ out)
{
    __shared__ __align__(16) unsigned short xs[32 * 132];
    const int t   = threadIdx.x;
    const int wid = t >> 6;          // 0..15
    const int m   = wid >> 2;        // matrix
    const int ct  = wid & 3;         // col tile
    const int l   = t & 63;
    const int col = ct * 32 + (l & 31);
    const int kb  = (l >> 5) * 8;

    v8bf b[8];
    {
        const unsigned short* wp = Wt + m * 16384 + col * 128 + kb;
        #pragma unroll
        for (int c = 0; c < 8; ++c) b[c] = *(const v8bf*)(wp + c * 16);
    }
    const float* bvec = (m == 0) ? bk : (m == 1) ? bq : (m == 2) ? bv : bs;
    const float bcol = bvec[col] * ((m == 0) ? -LOG2E : (m == 1) ? LOG2E : 1.0f);
    unsigned short* dst; int dstride;
    if (m == 0)      { dst = kws;      dstride = 128; }
    else if (m == 1) { dst = qv;       dstride = 256; }
    else             { dst = qv + 128; dstride = 256; }   // m==2 (v half)

    const int srow = t >> 5;         // 0..31
    const int sk4  = (t & 31) << 2;  // 0..124
    const int rowb = 4 * (l >> 5);

    const int ntiles = (N + 31) >> 5;
    int tile = blockIdx.x;
    if (tile >= ntiles) return;

    float4 stg = make_float4(0.f, 0.f, 0.f, 0.f);
    {
        int gr = tile * 32 + srow;
        if (gr < N) stg = *(const float4*)(x + (size_t)gr * 128 + sk4);
    }

    const unsigned short* ap = xs + (l & 31) * 132 + kb;

    while (true) {
        ushort4 pk;
        pk.x = f2bf(stg.x); pk.y = f2bf(stg.y);
        pk.z = f2bf(stg.z); pk.w = f2bf(stg.w);
        *(ushort4*)(xs + srow * 132 + sk4) = pk;
        __syncthreads();

        int next = tile + gridDim.x;
        if (next < ntiles) {
            int gr = next * 32 + srow;
            stg = (gr < N) ? *(const float4*)(x + (size_t)gr * 128 + sk4)
                           : make_float4(0.f, 0.f, 0.f, 0.f);
        }

        v16f acc = {};
        #pragma unroll
        for (int c = 0; c < 8; ++c) {
            v4bf a0 = *(const v4bf*)(ap + c * 16);
            v4bf a1 = *(const v4bf*)(ap + c * 16 + 4);
            v8bf a = __builtin_shufflevector(a0, a1, 0, 1, 2, 3, 4, 5, 6, 7);
            acc = __builtin_amdgcn_mfma_f32_32x32x16_bf16(a, b[c], acc, 0, 0, 0);
        }

        const int r0 = tile * 32 + rowb;
        if (m == 3) {
            #pragma unroll
            for (int reg = 0; reg < 16; ++reg) {
                int row = r0 + (reg & 3) + 8 * (reg >> 2);
                if (row < N) out[(size_t)row * 128 + col] = acc[reg] + bcol;
            }
        } else {
            #pragma unroll
            for (int reg = 0; reg < 16; ++reg) {
                int row = r0 + (reg & 3) + 8 * (reg >> 2);
                if (row < N) dst[(size_t)row * dstride + col] = f2bf(acc[reg] + bcol);
            }
        }

        tile = next;
        if (tile >= ntiles) break;
        __syncthreads();
    }
}

// ---------------- Phase 2: device-built CSR (single-atomic counting sort) ----------------

__global__ __launch_bounds__(256) void count_pos(
    const int* __restrict__ ei, int E, int* __restrict__ deg,
    int* __restrict__ pos)
{
    int e = blockIdx.x * 256 + threadIdx.x;
    if (e >= E) return;
    pos[e] = atomicAdd(&deg[ei[E + e]], 1);   // dst
}

__global__ __launch_bounds__(256) void scan_chunks(
    const int* __restrict__ deg, int N, int* __restrict__ rowStart,
    int* __restrict__ chunkTot)
{
    __shared__ int sums[256];
    const int t = threadIdx.x;
    const int base = blockIdx.x * 1024 + t * 4;
    int d0 = 0, d1 = 0, d2 = 0, d3 = 0;
    if (base + 3 < N) {
        int4 dd = *(const int4*)(deg + base);
        d0 = dd.x; d1 = dd.y; d2 = dd.z; d3 = dd.w;
    } else {
        if (base + 0 < N) d0 = deg[base + 0];
        if (base + 1 < N) d1 = deg[base + 1];
        if (base + 2 < N) d2 = deg[base + 2];
        if (base + 3 < N) d3 = deg[base + 3];
    }
    int tot = d0 + d1 + d2 + d3;
    sums[t] = tot;
    __syncthreads();
    #pragma unroll
    for (int off = 1; off < 256; off <<= 1) {
        int v = (t >= off) ? sums[t - off] : 0;
        __syncthreads();
        sums[t] += v;
        __syncthreads();
    }
    int excl = sums[t] - tot;
    if (base + 0 < N) rowStart[base + 0] = excl;
    if (base + 1 < N) rowStart[base + 1] = excl + d0;
    if (base + 2 < N) rowStart[base + 2] = excl + d0 + d1;
    if (base + 3 < N) rowStart[base + 3] = excl + d0 + d1 + d2;
    if (t == 255) chunkTot[blockIdx.x] = sums[255];
}

// add chunk offsets; each block re-scans the (<=128) chunk totals in LDS
__global__ __launch_bounds__(256) void add_offsets(
    int* __restrict__ rowStart, const int* __restrict__ chunkTot,
    int N, int nChunks)
{
    __shared__ int s[128];
    const int t = threadIdx.x;
    if (t < 128) s[t] = (t < nChunks) ? chunkTot[t] : 0;
    __syncthreads();
    #pragma unroll
    for (int off = 1; off < 128; off <<= 1) {
        int u = 0;
        if (t < 128 && t >= off) u = s[t - off];
        __syncthreads();
        if (t < 128) s[t] += u;
        __syncthreads();
    }
    const int coff = (blockIdx.x == 0) ? 0 : s[blockIdx.x - 1];
    const int base = blockIdx.x * 1024 + t * 4;
    if (base + 3 < N) {
        int4 r = *(const int4*)(rowStart + base);
        r.x += coff; r.y += coff; r.z += coff; r.w += coff;
        *(int4*)(rowStart + base) = r;
    } else {
        #pragma unroll
        for (int j = 0; j < 4; ++j) {
            if (base + j < N) rowStart[base + j] += coff;
        }
    }
}

// fill CSR (atomic-free scatter) + fused LOCAL degree-sort permutation:
// each 256-node window is counting-sorted by degree entirely in-block
// (LDS hist + wave-shfl scan). Keeps wave-level degree equality for the
// gather while confining perm to a 128KB out/kws window (L2-friendly).
__global__ __launch_bounds__(256) void fill_csr_perm(
    const int* __restrict__ ei, int E,
    const int* __restrict__ rowStart, const int* __restrict__ pos,
    int* __restrict__ elist,
    const int* __restrict__ deg, int N, int* __restrict__ perm)
{
    __shared__ int h[NBIN];
    __shared__ int boff[NBIN];
    const int t = threadIdx.x;
    const int nbase = blockIdx.x * 256;

    if (nbase < N) {                 // block-uniform branch (barriers safe)
        if (t < NBIN) h[t] = 0;
        __syncthreads();
        int i = nbase + t;
        int bin = 0, rank = 0;
        if (i < N) {
            bin = min(deg[i], NBIN - 1);
            rank = atomicAdd(&h[bin], 1);
        }
        __syncthreads();
        if (t < NBIN) {              // one wave: shfl inclusive scan -> exclusive
            int v = h[t];
            int inc = v;
            #pragma unroll
            for (int off = 1; off < NBIN; off <<= 1) {
                int u = __shfl_up(inc, off);
                if ((t & 63) >= off) inc += u;
            }
            boff[t] = inc - v;
        }
        __syncthreads();
        if (i < N) perm[nbase + boff[bin] + rank] = i;
    }

    int e = nbase + t;
    if (e < E) {
        int s = ei[e];
        int d = ei[E + e];
        elist[rowStart[d] + pos[e]] = s;   // atomic-free scatter
    }
}

// ---------------- Phase 3: owner-computes aggregation (no atomics) ----------------
// 4 nodes/wave (16 lanes each) in LOCALLY degree-sorted order. 3-stage
// decoupled pipeline per chunk-4 of edges:
//   IDX(n+2) prefetch  ||  GATHER(n+1) in flight  ||  COMP(n)
// The elist index load for a chunk is issued a full COMP (~300+ cy)
// before its gathers need it, so no address-dependent wait sits on the
// critical path (R4's LOADC fused idx-load+gather and stalled ~200cy per
// chunk on the index fetch). Two 32-VGPR gather buffers genuinely live.
__global__ __launch_bounds__(256, 4) void gather_agg(
    const int* __restrict__ perm,
    const int* __restrict__ rowStart, const int* __restrict__ deg,
    const int* __restrict__ elist,
    const unsigned short* __restrict__ kws,
    const unsigned short* __restrict__ qv,
    float* __restrict__ out, int N)
{
    int gid = blockIdx.x * 256 + threadIdx.x;
    int ni = gid >> 4;
    if (ni >= N) return;
    const int node = perm[ni];
    int fo = (gid & 15) << 3;   // 8 feats per lane

    u4v kraw = *(const u4v*)(kws + (size_t)node * 128 + fo);  // holds -k'
    const int p0 = rowStart[node];
    const int dg = deg[node];

    float nkf[8];
    unpack8v(kraw, nkf);
    float acc[8] = {};

    const unsigned short* qvb = qv + fo;
    const int e = p0 + dg;
    const int eL = e - 1;

    if (dg > 0) {
        int iA[4], iB[4];
        u4v qA[4], vA[4], qB[4], vB[4];

#define IDX(b, ix)                                                           \
        {                                                                    \
            _Pragma("unroll")                                                \
            for (int s = 0; s < 4; ++s) {                                    \
                int pp = (b) + s;                                            \
                ix[s] = elist[pp < e ? pp : eL];                             \
            }                                                                \
        }

#define GATHER(ix, qr, vr)                                                   \
        {                                                                    \
            _Pragma("unroll")                                                \
            for (int s = 0; s < 4; ++s) {                                    \
                const unsigned short* r = qvb + (ix[s] << 8);                \
                qr[s] = *(const u4v*)(r);                                    \
                vr[s] = *(const u4v*)(r + 128);                              \
            }                                                                \
        }

#define COMP(b, qr, vr)                                                     \
        {                                                                   \
            _Pragma("unroll")                                               \
            for (int s = 0; s < 4; ++s) {                                   \
                u4v vv = vr[s];                                             \
                if ((b) + s >= e) { vv[0]=0u; vv[1]=0u; vv[2]=0u; vv[3]=0u; } \
                float qf[8], vf[8];                                         \
                unpack8v(qr[s], qf);                                        \
                unpack8v(vv, vf);                                           \
                _Pragma("unroll")                                           \
                for (int j = 0; j < 8; ++j) {                               \
                    float ex = __builtin_amdgcn_exp2f(nkf[j] - qf[j]);      \
                    acc[j] = fmaf(__builtin_amdgcn_rcpf(1.0f + ex), vf[j], acc[j]); \
                }                                                           \
            }                                                               \
        }

        int base = p0;
        IDX(base, iA);
        GATHER(iA, qA, vA);
        int nb = base + 4;
        if (nb < e) IDX(nb, iB);
        while (true) {
            if (nb >= e) { COMP(base, qA, vA); break; }
            GATHER(iB, qB, vB);              // indices resident: no addr wait
            { int nn = nb + 4; if (nn < e) IDX(nn, iA); }  // prefetch n+2
            COMP(base, qA, vA);
            base = nb; nb += 4;
            if (nb >= e) { COMP(base, qB, vB); break; }
            GATHER(iA, qA, vA);
            { int nn = nb + 4; if (nn < e) IDX(nn, iB); }
            COMP(base, qB, vB);
            base = nb; nb += 4;
        }
#undef IDX
#undef GATHER
#undef COMP
    }

    // RMW kept tight: read -> add -> store (line stays hot in L2)
    float* orow = out + (size_t)node * 128 + fo;
    f4v o0 = *(const f4v*)(orow);
    f4v o1 = *(const f4v*)(orow + 4);
    o0[0] += acc[0]; o0[1] += acc[1]; o0[2] += acc[2]; o0[3] += acc[3];
    o1[0] += acc[4]; o1[1] += acc[5]; o1[2] += acc[6]; o1[3] += acc[7];
    *(f4v*)(orow)     = o0;
    *(f4v*)(orow + 4) = o1;
}

extern "C" void kernel_launch(void* const* d_in, const int* in_sizes, int n_in,
                              void* d_out, int out_size, void* d_ws, size_t ws_size,
                              hipStream_t stream) {
    const float* x    = (const float*)d_in[0];
    const int*   ei   = (const int*)d_in[1];
    const float* Wk   = (const float*)d_in[3];
    const float* bk   = (const float*)d_in[4];
    const float* Wq   = (const float*)d_in[5];
    const float* bq   = (const float*)d_in[6];
    const float* Wv   = (const float*)d_in[7];
    const float* bv   = (const float*)d_in[8];
    const float* Ws   = (const float*)d_in[9];
    const float* bias = (const float*)d_in[10];

    const int N = in_sizes[0] / 128;
    const int E = in_sizes[1] / 2;
    float* out = (float*)d_out;

    // workspace layout
    unsigned short* kws = (unsigned short*)d_ws;        // N*128 bf16 (-k', scaled)
    unsigned short* qv  = kws + (size_t)N * 128;        // N*256 bf16 (q'|v)
    int* deg      = (int*)(qv + (size_t)N * 256);
    int* rowStart = deg + N;
    int* chunkTot = rowStart + N;
    int* pos      = chunkTot + 128;                     // E ints (per-edge slot)
    int* elist    = pos + E;
    int* perm     = elist + E;                          // N ints (local sort)
    unsigned short* Wt = (unsigned short*)(perm + N);

    const int nChunks = (N + 1023) / 1024;

    prep_w_zero<<<512, 256, 0, stream>>>(Wk, Wq, Wv, Ws, Wt, deg, N);
    gemm_fused<<<1024, 1024, 0, stream>>>(
        x, N, Wt, bk, bq, bv, bias, kws, qv, out);

    count_pos<<<(E + 255) / 256, 256, 0, stream>>>(ei, E, deg, pos);
    scan_chunks<<<nChunks, 256, 0, stream>>>(deg, N, rowStart, chunkTot);
    add_offsets<<<nChunks, 256, 0, stream>>>(rowStart, chunkTot, N, nChunks);
    fill_csr_perm<<<(E + 255) / 256, 256, 0, stream>>>(
        ei, E, rowStart, pos, elist, deg, N, perm);

    gather_agg<<<((size_t)N * 16 + 255) / 256, 256, 0, stream>>>(
        perm, rowStart, deg, elist, kws, qv, out, N);
}

// Round 7
// 260.418 us; speedup vs baseline: 1.1168x; 1.0686x over previous
//
#include <hip/hip_runtime.h>
#include <hip/hip_bf16.h>

typedef __bf16 v4bf __attribute__((ext_vector_type(4)));
typedef __bf16 v8bf __attribute__((ext_vector_type(8)));
typedef float  v16f __attribute__((ext_vector_type(16)));
typedef float  f4v  __attribute__((ext_vector_type(4)));
typedef unsigned int u4v __attribute__((ext_vector_type(4)));

#define LOG2E 1.44269504088896340736f

// round-to-nearest-even float -> bf16 bits
__device__ __forceinline__ unsigned short f2bf(float f) {
    union { float f; unsigned int u; } a; a.f = f;
    unsigned int r = a.u + 0x7FFFu + ((a.u >> 16) & 1u);
    return (unsigned short)(r >> 16);
}

__device__ __forceinline__ void unpack8v(u4v w, float* f) {
    #pragma unroll
    for (int i = 0; i < 4; ++i) {
        f[2 * i]     = __uint_as_float(w[i] << 16);
        f[2 * i + 1] = __uint_as_float(w[i] & 0xFFFF0000u);
    }
}

// ---------------- Phase 0: pack W^T bf16 + zero deg (fused) ----------------
// k & q weights pre-scaled by log2(e); k additionally NEGATED so the
// gather kernel reads nk = -k' directly (sigmoid = rcp(1 + 2^(nk - q'))).
__global__ __launch_bounds__(256) void prep_w_zero(
    const float* __restrict__ Wk, const float* __restrict__ Wq,
    const float* __restrict__ Wv, const float* __restrict__ Ws,
    unsigned short* __restrict__ Wt, int* __restrict__ deg, int N)
{
    int i = blockIdx.x * 256 + threadIdx.x;      // 512 blocks -> 131072 threads
    if (i < 65536) {
        int m = i >> 14;
        int r = i & 16383;
        int n = r >> 7, k = r & 127;
        const float* W = (m == 0) ? Wk : (m == 1) ? Wq : (m == 2) ? Wv : Ws;
        float scale = (m == 0) ? -LOG2E : (m == 1) ? LOG2E : 1.0f;
        Wt[i] = f2bf(W[k * 128 + n] * scale);
    }
    if (i < N) deg[i] = 0;
}

// ---------------- Phase 1: fused MFMA GEMM + edge counting ----------------
// Edge degree-count + slot-capture (pure VMEM/atomic work) fused into the
// GEMM's head: it flies on the memory pipe while MFMA waves fill the
// matrix pipe, hiding what was a separate ~8us launch (R6 post-mortem).
__global__ __launch_bounds__(1024, 4) void gemm_fused(
    const float* __restrict__ x, int N,
    const unsigned short* __restrict__ Wt,
    const float* __restrict__ bk, const float* __restrict__ bq,
    const float* __restrict__ bv, const float* __restrict__ bs,
    unsigned short* __restrict__ kws, unsigned short* __restrict__ qv,
    float* __restrict__ out,
    const int* __restrict__ ei, int E,
    int* __restrict__ deg, int* __restrict__ pos)
{
    // fused counting-sort pass 1: one atomic per edge, also records the
    // edge's slot within its destination row (fill_csr is atomic-free).
    for (int e = blockIdx.x * 1024 + threadIdx.x; e < E; e += 1024 * 1024) {
        pos[e] = atomicAdd(&deg[ei[E + e]], 1);   // dst
    }

    __shared__ __align__(16) unsigned short xs[32 * 132];
    const int t   = threadIdx.x;
    const int wid = t >> 6;          // 0..15
    const int m   = wid >> 2;        // matrix
    const int ct  = wid & 3;         // col tile
    const int l   = t & 63;
    const int col = ct * 32 + (l & 31);
    const int kb  = (l >> 5) * 8;

    v8bf b[8];
    {
        const unsigned short* wp = Wt + m * 16384 + col * 128 + kb;
        #pragma unroll
        for (int c = 0; c < 8; ++c) b[c] = *(const v8bf*)(wp + c * 16);
    }
    const float* bvec = (m == 0) ? bk : (m == 1) ? bq : (m == 2) ? bv : bs;
    const float bcol = bvec[col] * ((m == 0) ? -LOG2E : (m == 1) ? LOG2E : 1.0f);
    unsigned short* dst; int dstride;
    if (m == 0)      { dst = kws;      dstride = 128; }
    else if (m == 1) { dst = qv;       dstride = 256; }
    else             { dst = qv + 128; dstride = 256; }   // m==2 (v half)

    const int srow = t >> 5;         // 0..31
    const int sk4  = (t & 31) << 2;  // 0..124
    const int rowb = 4 * (l >> 5);

    const int ntiles = (N + 31) >> 5;
    int tile = blockIdx.x;
    if (tile >= ntiles) return;

    float4 stg = make_float4(0.f, 0.f, 0.f, 0.f);
    {
        int gr = tile * 32 + srow;
        if (gr < N) stg = *(const float4*)(x + (size_t)gr * 128 + sk4);
    }

    const unsigned short* ap = xs + (l & 31) * 132 + kb;

    while (true) {
        ushort4 pk;
        pk.x = f2bf(stg.x); pk.y = f2bf(stg.y);
        pk.z = f2bf(stg.z); pk.w = f2bf(stg.w);
        *(ushort4*)(xs + srow * 132 + sk4) = pk;
        __syncthreads();

        int next = tile + gridDim.x;
        if (next < ntiles) {
            int gr = next * 32 + srow;
            stg = (gr < N) ? *(const float4*)(x + (size_t)gr * 128 + sk4)
                           : make_float4(0.f, 0.f, 0.f, 0.f);
        }

        v16f acc = {};
        #pragma unroll
        for (int c = 0; c < 8; ++c) {
            v4bf a0 = *(const v4bf*)(ap + c * 16);
            v4bf a1 = *(const v4bf*)(ap + c * 16 + 4);
            v8bf a = __builtin_shufflevector(a0, a1, 0, 1, 2, 3, 4, 5, 6, 7);
            acc = __builtin_amdgcn_mfma_f32_32x32x16_bf16(a, b[c], acc, 0, 0, 0);
        }

        // C/D: col = lane&31, row = (reg&3) + 8*(reg>>2) + 4*(lane>>5)
        const int r0 = tile * 32 + rowb;
        if (m == 3) {
            #pragma unroll
            for (int reg = 0; reg < 16; ++reg) {
                int row = r0 + (reg & 3) + 8 * (reg >> 2);
                if (row < N) out[(size_t)row * 128 + col] = acc[reg] + bcol;
            }
        } else {
            #pragma unroll
            for (int reg = 0; reg < 16; ++reg) {
                int row = r0 + (reg & 3) + 8 * (reg >> 2);
                if (row < N) dst[(size_t)row * dstride + col] = f2bf(acc[reg] + bcol);
            }
        }

        tile = next;
        if (tile >= ntiles) break;
        __syncthreads();
    }
}

// ---------------- Phase 2: CSR finish (scan + scatter, atomic-free) ----------------

__global__ __launch_bounds__(256) void scan_chunks(
    const int* __restrict__ deg, int N, int* __restrict__ rowStart,
    int* __restrict__ chunkTot)
{
    __shared__ int sums[256];
    const int t = threadIdx.x;
    const int base = blockIdx.x * 1024 + t * 4;
    int d0 = 0, d1 = 0, d2 = 0, d3 = 0;
    if (base + 3 < N) {
        int4 dd = *(const int4*)(deg + base);
        d0 = dd.x; d1 = dd.y; d2 = dd.z; d3 = dd.w;
    } else {
        if (base + 0 < N) d0 = deg[base + 0];
        if (base + 1 < N) d1 = deg[base + 1];
        if (base + 2 < N) d2 = deg[base + 2];
        if (base + 3 < N) d3 = deg[base + 3];
    }
    int tot = d0 + d1 + d2 + d3;
    sums[t] = tot;
    __syncthreads();
    #pragma unroll
    for (int off = 1; off < 256; off <<= 1) {
        int v = (t >= off) ? sums[t - off] : 0;
        __syncthreads();
        sums[t] += v;
        __syncthreads();
    }
    int excl = sums[t] - tot;
    if (base + 0 < N) rowStart[base + 0] = excl;
    if (base + 1 < N) rowStart[base + 1] = excl + d0;
    if (base + 2 < N) rowStart[base + 2] = excl + d0 + d1;
    if (base + 3 < N) rowStart[base + 3] = excl + d0 + d1 + d2;
    if (t == 255) chunkTot[blockIdx.x] = sums[255];
}

// add chunk offsets; each block re-scans the (<=128) chunk totals in LDS
__global__ __launch_bounds__(256) void add_offsets(
    int* __restrict__ rowStart, const int* __restrict__ chunkTot,
    int N, int nChunks)
{
    __shared__ int s[128];
    const int t = threadIdx.x;
    if (t < 128) s[t] = (t < nChunks) ? chunkTot[t] : 0;
    __syncthreads();
    #pragma unroll
    for (int off = 1; off < 128; off <<= 1) {
        int u = 0;
        if (t < 128 && t >= off) u = s[t - off];
        __syncthreads();
        if (t < 128) s[t] += u;
        __syncthreads();
    }
    const int coff = (blockIdx.x == 0) ? 0 : s[blockIdx.x - 1];
    const int base = blockIdx.x * 1024 + t * 4;
    if (base + 3 < N) {
        int4 r = *(const int4*)(rowStart + base);
        r.x += coff; r.y += coff; r.z += coff; r.w += coff;
        *(int4*)(rowStart + base) = r;
    } else {
        #pragma unroll
        for (int j = 0; j < 4; ++j) {
            if (base + j < N) rowStart[base + j] += coff;
        }
    }
}

__global__ __launch_bounds__(256) void fill_csr(
    const int* __restrict__ ei, int E,
    const int* __restrict__ rowStart, const int* __restrict__ pos,
    int* __restrict__ elist)
{
    int e = blockIdx.x * 256 + threadIdx.x;
    if (e >= E) return;
    elist[rowStart[ei[E + e]] + pos[e]] = ei[e];   // atomic-free scatter
}

// ---------------- Phase 3: owner-computes aggregation (no atomics) ----------------
// NATURAL node order (R6 post-mortem: the perm indirection cost ~+15us at
// equal traffic by breaking out/kws streaming across adjacent groups).
// 4 nodes/wave (16 lanes each), lane owns 8 feats. Grid-stride persistent
// blocks (1024): next node's metadata loads overlap current node's edge
// loop. Exact-trip chunk-4 loop (clamped index, zeroed v for pad slots:
// only ~1.16x slot inflation, no serial remainder). out RMW read hoisted
// to node start — with natural order this measured WRITE=50MB (R0/R1),
// no store amplification.
__global__ __launch_bounds__(256, 4) void gather_agg(
    const int* __restrict__ rowStart, const int* __restrict__ deg,
    const int* __restrict__ elist,
    const unsigned short* __restrict__ kws,
    const unsigned short* __restrict__ qv,
    float* __restrict__ out, int N)
{
    const int grp = threadIdx.x >> 4;            // 0..15 group within block
    const int fo  = (threadIdx.x & 15) << 3;     // 8 feats per lane
    const int gstride = gridDim.x * 16;
    const unsigned short* qvb = qv + fo;

    for (int node = blockIdx.x * 16 + grp; node < N; node += gstride) {
        // independent long-latency loads first
        float* orow = out + (size_t)node * 128 + fo;
        f4v o0 = *(const f4v*)(orow);
        f4v o1 = *(const f4v*)(orow + 4);
        u4v kraw = *(const u4v*)(kws + (size_t)node * 128 + fo);  // holds -k'
        const int p0 = rowStart[node];
        const int dg = deg[node];
        const int e  = p0 + dg;
        const int eL = e - 1;

        float nkf[8];
        unpack8v(kraw, nkf);
        float acc[8] = {};

        for (int base = p0; base < e; base += 4) {
            int idx[4];
            #pragma unroll
            for (int s = 0; s < 4; ++s) {
                int pp = base + s;
                idx[s] = elist[pp < e ? pp : eL];   // clamped: in-bounds
            }
            u4v qr[4], vr[4];
            #pragma unroll
            for (int s = 0; s < 4; ++s) {
                const unsigned short* r = qvb + (idx[s] << 8);
                qr[s] = *(const u4v*)(r);
                vr[s] = *(const u4v*)(r + 128);
            }
            #pragma unroll
            for (int s = 0; s < 4; ++s) {
                u4v vv = vr[s];
                if (base + s >= e) { vv[0] = 0u; vv[1] = 0u; vv[2] = 0u; vv[3] = 0u; }
                float qf[8], vf[8];
                unpack8v(qr[s], qf);
                unpack8v(vv, vf);
                #pragma unroll
                for (int j = 0; j < 8; ++j) {
                    float ex = __builtin_amdgcn_exp2f(nkf[j] - qf[j]);
                    acc[j] = fmaf(__builtin_amdgcn_rcpf(1.0f + ex), vf[j], acc[j]);
                }
            }
        }

        o0[0] += acc[0]; o0[1] += acc[1]; o0[2] += acc[2]; o0[3] += acc[3];
        o1[0] += acc[4]; o1[1] += acc[5]; o1[2] += acc[6]; o1[3] += acc[7];
        *(f4v*)(orow)     = o0;
        *(f4v*)(orow + 4) = o1;
    }
}

extern "C" void kernel_launch(void* const* d_in, const int* in_sizes, int n_in,
                              void* d_out, int out_size, void* d_ws, size_t ws_size,
                              hipStream_t stream) {
    const float* x    = (const float*)d_in[0];
    const int*   ei   = (const int*)d_in[1];
    const float* Wk   = (const float*)d_in[3];
    const float* bk   = (const float*)d_in[4];
    const float* Wq   = (const float*)d_in[5];
    const float* bq   = (const float*)d_in[6];
    const float* Wv   = (const float*)d_in[7];
    const float* bv   = (const float*)d_in[8];
    const float* Ws   = (const float*)d_in[9];
    const float* bias = (const float*)d_in[10];

    const int N = in_sizes[0] / 128;
    const int E = in_sizes[1] / 2;
    float* out = (float*)d_out;

    // workspace layout
    unsigned short* kws = (unsigned short*)d_ws;        // N*128 bf16 (-k', scaled)
    unsigned short* qv  = kws + (size_t)N * 128;        // N*256 bf16 (q'|v)
    int* deg      = (int*)(qv + (size_t)N * 256);
    int* rowStart = deg + N;
    int* chunkTot = rowStart + N;
    int* pos      = chunkTot + 128;                     // E ints (per-edge slot)
    int* elist    = pos + E;
    unsigned short* Wt = (unsigned short*)(elist + E);

    const int nChunks = (N + 1023) / 1024;

    prep_w_zero<<<512, 256, 0, stream>>>(Wk, Wq, Wv, Ws, Wt, deg, N);
    gemm_fused<<<1024, 1024, 0, stream>>>(
        x, N, Wt, bk, bq, bv, bias, kws, qv, out, ei, E, deg, pos);

    scan_chunks<<<nChunks, 256, 0, stream>>>(deg, N, rowStart, chunkTot);
    add_offsets<<<nChunks, 256, 0, stream>>>(rowStart, chunkTot, N, nChunks);
    fill_csr<<<(E + 255) / 256, 256, 0, stream>>>(ei, E, rowStart, pos, elist);

    gather_agg<<<1024, 256, 0, stream>>>(
        rowStart, deg, elist, kws, qv, out, N);
}